// Round 5
// baseline (78.320 us; speedup 1.0000x reference)
//
#include <hip/hip_runtime.h>

typedef __bf16 bf16x8 __attribute__((ext_vector_type(8)));
typedef float f32x16 __attribute__((ext_vector_type(16)));

#define S_TOTAL 8192
#define DIM 256
#define BK 64

__global__ __launch_bounds__(256) void zero_out(float* __restrict__ out) {
    out[blockIdx.x * 256 + threadIdx.x] = 0.0f;
}

// Block = (batch, k-chunk): full 256x256 f32 partial via bf16 MFMA, pre-scaled,
// atomicAdd'ed straight into out (2MB f32, L2/L3-resident -> no ws round-trip).
// R3's proven interior: 1024 thr = 16 waves (4x4 of 64x64 tiles), subtiled bf16
// LDS [mat][kb=8][i=256][e=8] (ds_write_b128/ds_read_b128 lane-linear, 0 conflicts),
// reg-staged loads issued before compute (T14).
__global__ __launch_bounds__(1024) void opm_partial(
    const float* __restrict__ A, const float* __restrict__ Bm,
    float* __restrict__ out, int split, int kc, float scale)
{
    __shared__ __bf16 lds[2][8 * 256 * 8];   // 2 x 32 KB (A-half, B-half)

    const int tid = threadIdx.x;
    const int w   = tid >> 6;
    const int l   = tid & 63;
    const int batch = blockIdx.x / split;
    const int sp    = blockIdx.x % split;
    const long long base = (long long)batch * S_TOTAL * DIM;
    const int s0 = sp * kc;
    const int wr = w >> 2, wc = w & 3;     // wave position in 4x4 grid
    const int lane31 = l & 31;
    const int hi = l >> 5;
    const int niter = kc / BK;

    // staging roles: waves 0-7 stage A (kb=w), 8-15 stage B; lane owns cols {l, l+64, l+128, l+192}
    const int mat = w >> 3;
    const int kb  = w & 7;
    const float* src = mat ? Bm : A;
    __bf16* dstl = &lds[mat][0];

    f32x16 acc[2][2] = {};
    float r[32];

    auto loadreg = [&](int it) {
        const long long rowbase = base + (long long)(s0 + it * BK + kb * 8) * DIM + l;
        #pragma unroll
        for (int c = 0; c < 4; ++c)
            #pragma unroll
            for (int e = 0; e < 8; ++e)
                r[c * 8 + e] = src[rowbase + e * DIM + c * 64];
    };
    auto cvtwrite = [&]() {
        #pragma unroll
        for (int c = 0; c < 4; ++c) {
            bf16x8 v;
            #pragma unroll
            for (int e = 0; e < 8; ++e) v[e] = (__bf16)r[c * 8 + e];
            *(bf16x8*)&dstl[(kb * 256 + l + c * 64) * 8] = v;
        }
    };
    auto compute = [&]() {
        #pragma unroll
        for (int t = 0; t < 4; ++t) {          // 4 k-tiles of 16 within BK=64
            const int kb0 = t * 2 + hi;
            bf16x8 af[2], bfv[2];
            #pragma unroll
            for (int mi = 0; mi < 2; ++mi)
                af[mi] = *(const bf16x8*)&lds[0][(kb0 * 256 + wr * 64 + mi * 32 + lane31) * 8];
            #pragma unroll
            for (int nj = 0; nj < 2; ++nj)
                bfv[nj] = *(const bf16x8*)&lds[1][(kb0 * 256 + wc * 64 + nj * 32 + lane31) * 8];
            #pragma unroll
            for (int mi = 0; mi < 2; ++mi)
                #pragma unroll
                for (int nj = 0; nj < 2; ++nj)
                    acc[mi][nj] = __builtin_amdgcn_mfma_f32_32x32x16_bf16(
                        af[mi], bfv[nj], acc[mi][nj], 0, 0, 0);
        }
    };

    loadreg(0);
    cvtwrite();
    __syncthreads();

    for (int it = 0; it < niter; ++it) {
        if (it + 1 < niter) loadreg(it + 1);   // issue early — lands during compute
        __builtin_amdgcn_sched_barrier(0);
        compute();
        __syncthreads();
        if (it + 1 < niter) {
            cvtwrite();
            __syncthreads();
        }
    }

    // ---- epilogue: pre-scale and atomically accumulate into out ----
    float* o = out + (long long)batch * (256 * 256);
    #pragma unroll
    for (int mi = 0; mi < 2; ++mi)
    #pragma unroll
    for (int nj = 0; nj < 2; ++nj)
    #pragma unroll
    for (int q = 0; q < 16; ++q) {
        const int row = (q & 3) + 8 * (q >> 2) + 4 * hi;
        const int i = wr * 64 + mi * 32 + row;
        const int j = wc * 64 + nj * 32 + lane31;
        atomicAdd(&o[i * 256 + j], acc[mi][nj][q] * scale);
    }
}

extern "C" void kernel_launch(void* const* d_in, const int* in_sizes, int n_in,
                              void* d_out, int out_size, void* d_ws, size_t ws_size,
                              hipStream_t stream)
{
    (void)in_sizes; (void)n_in; (void)d_ws; (void)ws_size; (void)out_size;
    const float* A  = (const float*)d_in[0];
    const float* Bm = (const float*)d_in[1];
    float* out = (float*)d_out;

    const int split = 32;                 // grid = 8*32 = 256 blocks = 1/CU
    const int kc = S_TOTAL / split;       // 256

    zero_out<<<8 * 256, 256, 0, stream>>>(out);
    opm_partial<<<8 * split, 1024, 0, stream>>>(A, Bm, out, split, kc, 1.0f / 8192.0f);
}

// Round 6
// 41.781 us; speedup vs baseline: 1.8745x; 1.8745x over previous
//
#include <hip/hip_runtime.h>

typedef __bf16 bf16x8 __attribute__((ext_vector_type(8)));
typedef float f32x16 __attribute__((ext_vector_type(16)));
typedef float f32x4 __attribute__((ext_vector_type(4)));

#define S_TOTAL 8192
#define DIM 256
#define BK 32

// Block = (batch, k-chunk): full 256x256 partial via bf16 MFMA into bf16 ws.
// 1024 thr = 16 waves (4x4 of 64x64 tiles). Subtiled bf16 LDS
// [buf][mat][kb2=4][i=256][e=8]: ds_write_b128 / ds_read_b128 lane-linear, 0 conflicts.
// Double-buffered LDS + 2-deep register prefetch (named rA/rB sets), raw s_barrier
// with lgkmcnt(0)-only wait -> in-flight global loads are never drained at barriers.
__global__ __launch_bounds__(1024) void opm_partial(
    const float* __restrict__ A, const float* __restrict__ Bm,
    __bf16* __restrict__ dstbf, float* __restrict__ dstf32,
    int split, int kc, float scale)
{
    __shared__ __bf16 lds[2][2][4 * 256 * 8];   // 2 buf x 2 mat x 16 KB

    const int tid = threadIdx.x;
    const int w   = tid >> 6;
    const int l   = tid & 63;
    const int batch = blockIdx.x / split;
    const int sp    = blockIdx.x % split;
    const long long base = (long long)batch * S_TOTAL * DIM;
    const int s0 = sp * kc;
    const int wr = w >> 2, wc = w & 3;     // wave position in 4x4 grid
    const int lane31 = l & 31;
    const int hi = l >> 5;
    const int niter = kc / BK;             // 8 (even)

    // staging roles: mat = w>>3 (0:A, 1:B); row-group g = (w&7)>>1 (8 s-rows);
    // col half = w&1; lane owns cols {c0, c0+64}.
    const int mat = w >> 3;
    const int g   = (w & 7) >> 1;
    const int c0  = (w & 1) * 128 + l;
    const float* src = mat ? Bm : A;

    f32x16 acc[2][2] = {};
    float rA[16], rB[16];

#define LOAD(r, it) do {                                                        \
    const long long rowbase = base + (long long)(s0 + (it) * BK + g * 8) * DIM; \
    _Pragma("unroll")                                                           \
    for (int e = 0; e < 8; ++e) {                                               \
        r[e]     = src[rowbase + e * DIM + c0];                                 \
        r[8 + e] = src[rowbase + e * DIM + c0 + 64];                            \
    }                                                                           \
} while (0)

#define CVTWRITE(r, buf) do {                                                   \
    bf16x8 v0, v1;                                                              \
    _Pragma("unroll")                                                           \
    for (int e = 0; e < 8; ++e) { v0[e] = (__bf16)r[e]; v1[e] = (__bf16)r[8 + e]; } \
    *(bf16x8*)&lds[buf][mat][(g * 256 + c0) * 8]      = v0;                     \
    *(bf16x8*)&lds[buf][mat][(g * 256 + c0 + 64) * 8] = v1;                     \
} while (0)

#define BAR() do {                                                              \
    asm volatile("s_waitcnt lgkmcnt(0)" ::: "memory");                          \
    __builtin_amdgcn_s_barrier();                                               \
} while (0)

    auto compute = [&](int buf) {
        #pragma unroll
        for (int t = 0; t < 2; ++t) {          // 2 k-tiles of 16 within BK=32
            const int kb2 = t * 2 + hi;
            bf16x8 af[2], bfv[2];
            #pragma unroll
            for (int mi = 0; mi < 2; ++mi)
                af[mi] = *(const bf16x8*)&lds[buf][0][(kb2 * 256 + wr * 64 + mi * 32 + lane31) * 8];
            #pragma unroll
            for (int nj = 0; nj < 2; ++nj)
                bfv[nj] = *(const bf16x8*)&lds[buf][1][(kb2 * 256 + wc * 64 + nj * 32 + lane31) * 8];
            #pragma unroll
            for (int mi = 0; mi < 2; ++mi)
                #pragma unroll
                for (int nj = 0; nj < 2; ++nj)
                    acc[mi][nj] = __builtin_amdgcn_mfma_f32_32x32x16_bf16(
                        af[mi], bfv[nj], acc[mi][nj], 0, 0, 0);
        }
    };

    // prologue: tile0 -> buf0; tile1 loads in flight
    LOAD(rA, 0);
    LOAD(rB, 1);
    CVTWRITE(rA, 0);        // waits only rA's loads (rB stays outstanding)
    BAR();

    for (int bs = 0; bs < niter; bs += 2) {
        // even phase: compute tile bs (buf0); publish tile bs+1 (buf1); issue bs+2
        if (bs + 2 < niter) LOAD(rA, bs + 2);
        compute(0);
        CVTWRITE(rB, 1);
        BAR();
        // odd phase: compute tile bs+1 (buf1); publish tile bs+2 (buf0); issue bs+3
        if (bs + 3 < niter) LOAD(rB, bs + 3);
        compute(1);
        if (bs + 2 < niter) { CVTWRITE(rA, 0); }
        BAR();
    }

#undef LOAD
#undef CVTWRITE
#undef BAR

    // ---- epilogue ----
    const long long obase = (long long)blockIdx.x * (256 * 256);
    if (dstf32) {
        float* o = dstf32 + obase;
        #pragma unroll
        for (int mi = 0; mi < 2; ++mi)
        #pragma unroll
        for (int nj = 0; nj < 2; ++nj)
        #pragma unroll
        for (int q = 0; q < 16; ++q) {
            const int row = (q & 3) + 8 * (q >> 2) + 4 * hi;
            const int i = wr * 64 + mi * 32 + row;
            const int j = wc * 64 + nj * 32 + lane31;
            o[i * 256 + j] = acc[mi][nj][q] * scale;
        }
    } else {
        __bf16* o = dstbf + obase;
        #pragma unroll
        for (int mi = 0; mi < 2; ++mi)
        #pragma unroll
        for (int nj = 0; nj < 2; ++nj)
        #pragma unroll
        for (int q = 0; q < 16; ++q) {
            const int row = (q & 3) + 8 * (q >> 2) + 4 * hi;
            const int i = wr * 64 + mi * 32 + row;
            const int j = wc * 64 + nj * 32 + lane31;
            o[i * 256 + j] = (__bf16)(acc[mi][nj][q] * scale);
        }
    }
}

// Sum `split` bf16 partials per batch, scale by 1/8192. bf16x8 (16B) per lane.
__global__ __launch_bounds__(256) void opm_reduce(
    const __bf16* __restrict__ ws, float* __restrict__ out, int split)
{
    const int idx = blockIdx.x * 256 + threadIdx.x;   // 65536 groups of 8 f32
    const int b = idx >> 13;                          // 8192 groups per batch
    const int r = idx & 8191;
    const bf16x8* p = (const bf16x8*)ws + (long long)b * split * 8192 + r;
    float s[8] = {0.f, 0.f, 0.f, 0.f, 0.f, 0.f, 0.f, 0.f};
    for (int sp = 0; sp < split; ++sp) {
        bf16x8 v = p[(long long)sp * 8192];
        #pragma unroll
        for (int e = 0; e < 8; ++e) s[e] += (float)v[e];
    }
    f32x4 lo = { s[0], s[1], s[2], s[3] };
    f32x4 hiv = { s[4], s[5], s[6], s[7] };
    lo  *= (1.0f / 8192.0f);
    hiv *= (1.0f / 8192.0f);
    ((f32x4*)out)[idx * 2]     = lo;
    ((f32x4*)out)[idx * 2 + 1] = hiv;
}

extern "C" void kernel_launch(void* const* d_in, const int* in_sizes, int n_in,
                              void* d_out, int out_size, void* d_ws, size_t ws_size,
                              hipStream_t stream)
{
    (void)in_sizes; (void)n_in; (void)out_size;
    const float* A  = (const float*)d_in[0];
    const float* Bm = (const float*)d_in[1];
    float* out = (float*)d_out;

    int split = 32;
    while (split > 1 && (size_t)8 * split * 65536 * sizeof(__bf16) > ws_size) split >>= 1;

    if (split >= 2) {
        const int kc = S_TOTAL / split;
        opm_partial<<<8 * split, 1024, 0, stream>>>(A, Bm, (__bf16*)d_ws, nullptr, split, kc, 1.0f);
        opm_reduce<<<256, 256, 0, stream>>>((const __bf16*)d_ws, out, split);
    } else {
        // tiny-ws fallback: one block per batch over full K, f32 direct to out
        opm_partial<<<8, 1024, 0, stream>>>(A, Bm, nullptr, out, 1, S_TOTAL, 1.0f / 8192.0f);
    }
}